// Round 4
// baseline (603.048 us; speedup 1.0000x reference)
//
#include <hip/hip_runtime.h>
#include <cstdint>
#include <cstddef>

// FlowNet-C correlation, MI355X — round 7: bf16x3 MFMA band-GEMM.
// B=8 C=256 H=64 W=96, PAD=MAXD=20, K=1, S1=1, S2=2 -> 441 output channels.
// out[b, dy*21+dx, y, x] = (1/256) * sum_c in1[b,c,y,x] * in2[b,c,y+2(dy-10), x+2(dx-10)]
//
// R3-R6 conclusion: fp32-VALU path is LDS-port bound (~128B/cyc/CU feeding 4
// SIMDs; best feasible tile = 8 FMA per b128 read -> ~280us floor; bigger
// register tiles spill (R4/R5)). Past it only via matrix cores: fp32 split into
// bf16 hi+lo, 3 MFMA passes (ah*bh + ah*bl + al*bh), residual ~2^-16 relative
// -> absmax unchanged vs fp32 path.
//
// Structure: x2 = x + 2(dx-10) preserves parity -> per (b,y,p): banded GEMM
// out[u,dx] = sum_c A[u,c]*B[u+dx-10,c], u,v in [0,48). 16x16x32 tiles: only 7
// (m,v) tiles needed per dy. Block = (b,y,p), 448 thr = 7 waves = 7 tiles.
//  - A (dy-invariant) hi/lo planes staged once; A-frags loaded ONCE into 64
//    VGPRs, resident across all dy -> k-loop reads only B: 2 b128/wave/k-step.
//  - B hi/lo double-buffered; T14 split staging (issue 8-dword rounds between
//    k-step pairs, convert+ds_write after) hides L2 latency under MFMA.
//  - granule-XOR swizzle (addr16 = r*32 + (g ^ (r&7))) on BOTH write and read.
//  - epilogue: accs -> 21x49 LDS grid (band-edge zeros for free) -> row writes.
//  - invalid y2 rows (16% of (y,dy)) skipped; their outputs zero-filled.

typedef short bf16x8 __attribute__((ext_vector_type(8)));
typedef float f32x4  __attribute__((ext_vector_type(4)));

constexpr int B_ = 8, C_ = 256, H_ = 64, W_ = 96, D_ = 21;
constexpr int THREADS = 448;                 // 7 waves
constexpr int CSTR = H_ * W_;                // 6144 floats per channel plane
constexpr size_t IMG = (size_t)C_ * CSTR;    // floats per batch image

// LDS granule(16B) indices: plane = 48 rows x 32 granules = 1536
constexpr int AHI = 0;                       // A_lo = +1536
constexpr int BHI0 = 3072;                   // buf d: hi = 3072+d*3072, lo = +1536

__global__ __launch_bounds__(THREADS, 1) void corr_mfma(
    const float* __restrict__ in1,
    const float* __restrict__ in2,
    float* __restrict__ out)
{
    __shared__ uint4 ldsq[9216];             // 147,456 B
    __shared__ float lout[D_ * 49];          // 4,116 B (49: bank-spread pad)

    const int id  = blockIdx.x;
    const int b   = id & 7;                  // XCD gets one batch -> L2 window
    const int p   = (id >> 3) & 1;           // parity sibling adjacent
    const int y   = id >> 4;                 // y-major
    const int tid = threadIdx.x;
    const int lane = tid & 63, li = lane & 15, gl = lane >> 4, wid = tid >> 6;

    // wave -> (m-tile, v-tile): 7 useful band tiles of the 3x3 grid
    const int mw = (wid < 2) ? 0 : (wid < 5) ? 16 : 32;
    const int vw = (wid == 0 || wid == 2) ? 0 : (wid == 4) ? 32
                 : (wid == 6) ? 32 : 16;     // {0,16,0,16,32,16,32}

    const int dylo = (y >= 21) ? 0 : ((21 - y) >> 1);
    const int dyhi = min(20, (83 - y) >> 1);

    // ---- fp32 -> bf16 hi/lo split + LDS store (16B granule, swizzled) ----
    auto cvt = [&](const float (&f)[8], int gdst) {
        uint hv[4], lv[4];
        #pragma unroll
        for (int q = 0; q < 4; ++q) {
            uint a0 = __float_as_uint(f[2*q]), a1 = __float_as_uint(f[2*q+1]);
            hv[q] = (a1 & 0xFFFF0000u) | (a0 >> 16);
            float r0 = f[2*q]   - __uint_as_float(a0 & 0xFFFF0000u);
            float r1 = f[2*q+1] - __uint_as_float(a1 & 0xFFFF0000u);
            lv[q] = (__float_as_uint(r1) & 0xFFFF0000u) | (__float_as_uint(r0) >> 16);
        }
        ldsq[gdst]        = uint4{hv[0], hv[1], hv[2], hv[3]};
        ldsq[gdst + 1536] = uint4{lv[0], lv[1], lv[2], lv[3]};
    };

    // serial staging of one 48x256 tile (src: + c*CSTR + 2*v addressing)
    auto stage_now = [&](const float* src, int hiPlane) {
        #pragma unroll
        for (int r = 0; r < 4; ++r) {
            int t = tid + r * THREADS;
            if (t < 1536) {
                int v = t >> 5, cg = t & 31;
                const float* g = src + (size_t)cg * 8 * CSTR + 2 * v;
                float f[8];
                #pragma unroll
                for (int j = 0; j < 8; ++j) f[j] = g[(size_t)j * CSTR];
                cvt(f, hiPlane + v * 32 + (cg ^ (v & 7)));
            }
        }
    };

    // ---- prologue: stage A, stage B(dylo) -> buf0, zero lout ----
    stage_now(in1 + (size_t)b * IMG + (size_t)y * W_ + p, AHI);
    stage_now(in2 + (size_t)b * IMG + (size_t)(y + 2 * dylo - 20) * W_ + p, BHI0);
    for (int z = tid; z < D_ * 49; z += THREADS) lout[z] = 0.f;
    __syncthreads();

    // ---- A-fragments: resident across the whole dy loop (64 VGPR) ----
    bf16x8 ah[8], al[8];
    {
        const int rA = mw + li;
        #pragma unroll
        for (int k0 = 0; k0 < 8; ++k0) {
            int off = rA * 32 + (((4 * k0 + gl)) ^ (rA & 7));
            ah[k0] = *(const bf16x8*)&ldsq[AHI + off];
            al[k0] = *(const bf16x8*)&ldsq[AHI + 1536 + off];
        }
    }

    // B-frag read offsets (granule units, swizzled)
    int offB[8];
    {
        const int rB = vw + li;
        #pragma unroll
        for (int k0 = 0; k0 < 8; ++k0)
            offB[k0] = rB * 32 + (((4 * k0 + gl)) ^ (rB & 7));
    }

    // ---- prefetch descriptors: 1536 tasks in 4 rounds, scalar state ----
    const float *pp0, *pp1, *pp2, *pp3;
    int pg0, pg1, pg2, pg3;
    bool ok0, ok1, ok2, ok3;
    {
        const float* base2 = in2 + (size_t)b * IMG
                           + (size_t)(y + 2 * dylo - 18) * W_ + p; // y2(dylo+1)
        #define PINIT(n) { int t = tid + n * THREADS; ok##n = t < 1536;          \
            int v = t >> 5, cg = t & 31;                                          \
            pp##n = base2 + (size_t)cg * 8 * CSTR + 2 * v;                        \
            pg##n = v * 32 + (cg ^ (v & 7)); }
        PINIT(0) PINIT(1) PINIT(2) PINIT(3)
        #undef PINIT
    }

    #define ISSUE(n, F) if (pref && ok##n) { _Pragma("unroll")                    \
        for (int j = 0; j < 8; ++j) F[j] = pp##n[(size_t)j * CSTR]; }
    #define FINISH(n, F) { if (pref && ok##n) cvt(F, nxtHI + pg##n);              \
        pp##n += 2 * W_; }
    #define KSTEP(k0) {                                                           \
        bf16x8 bh = *(const bf16x8*)&ldsq[curHI + offB[k0]];                      \
        bf16x8 bl = *(const bf16x8*)&ldsq[curHI + 1536 + offB[k0]];               \
        accB = __builtin_amdgcn_mfma_f32_16x16x32_bf16(al[k0], bh, accB, 0,0,0);  \
        accB = __builtin_amdgcn_mfma_f32_16x16x32_bf16(ah[k0], bl, accB, 0,0,0);  \
        accA = __builtin_amdgcn_mfma_f32_16x16x32_bf16(ah[k0], bh, accA, 0,0,0); }

    // ---- dy loop ----
    int cur = 0;
    float fA[8], fB[8];
    for (int dy = dylo; dy <= dyhi; ++dy) {
        const bool pref = dy < dyhi;
        const int curHI = BHI0 + cur * 3072;
        const int nxtHI = BHI0 + (cur ^ 1) * 3072;
        f32x4 accA = {0.f, 0.f, 0.f, 0.f}, accB = {0.f, 0.f, 0.f, 0.f};

        ISSUE(0, fA)  KSTEP(0) KSTEP(1)
        FINISH(0, fA) ISSUE(1, fB)  KSTEP(2) KSTEP(3)
        FINISH(1, fB) ISSUE(2, fA)  KSTEP(4) KSTEP(5)
        FINISH(2, fA) ISSUE(3, fB)  KSTEP(6) KSTEP(7)
        FINISH(3, fB)

        // scatter: C/D map col=lane&15 -> v, row=(lane>>4)*4+r -> u (m89)
        #pragma unroll
        for (int rr = 0; rr < 4; ++rr) {
            int u  = mw + gl * 4 + rr;
            int v  = vw + li;
            int dx = v - u + 10;
            if ((unsigned)dx < 21u)
                lout[dx * 49 + u] = (accA[rr] + accB[rr]) * (1.f / 256.f);
        }
        __syncthreads();

        // write 21 dx rows (3 per wave), then re-zero for next dy
        if (lane < 48) {
            #pragma unroll
            for (int q = 0; q < 3; ++q) {
                int dx = wid + 7 * q;
                float val = lout[dx * 49 + lane];
                out[(((size_t)(b * 441 + dy * D_ + dx)) * H_ + y) * W_
                    + p + 2 * lane] = val;
                lout[dx * 49 + lane] = 0.f;
            }
        }
        __syncthreads();
        cur ^= 1;
    }
    #undef ISSUE
    #undef FINISH
    #undef KSTEP

    // ---- invalid-dy outputs are zero ----
    for (int dy = 0; dy < D_; ++dy) {
        if (dy >= dylo && dy <= dyhi) continue;
        for (int z = tid; z < D_ * 48; z += THREADS) {
            int dx = z / 48, u = z - dx * 48;
            out[(((size_t)(b * 441 + dy * D_ + dx)) * H_ + y) * W_
                + p + 2 * u] = 0.f;
        }
    }
}

extern "C" void kernel_launch(void* const* d_in, const int* in_sizes, int n_in,
                              void* d_out, int out_size, void* d_ws, size_t ws_size,
                              hipStream_t stream) {
    const float* in1 = (const float*)d_in[0];
    const float* in2 = (const float*)d_in[1];
    float* out = (float*)d_out;
    (void)in_sizes; (void)n_in; (void)d_ws; (void)ws_size; (void)out_size;
    dim3 grid(B_ * H_ * 2);                  // 1024: b fastest, then p, then y
    corr_mfma<<<grid, dim3(THREADS), 0, stream>>>(in1, in2, out);
}

// Round 5
// 336.611 us; speedup vs baseline: 1.7915x; 1.7915x over previous
//
#include <hip/hip_runtime.h>
#include <cstdint>
#include <cstddef>

// FlowNet-C correlation, MI355X — round 8: bf16x3 MFMA band-GEMM, fed properly.
// B=8 C=256 H=64 W=96, PAD=MAXD=20, K=1, S1=1, S2=2 -> 441 output channels.
// out[b, dy*21+dx, y, x] = (1/256) * sum_c in1[b,c,y,x] * in2[b,c,y+2(dy-10), x+2(dx-10)]
//
// R7 post-mortem (505us, MfmaUtil 4%, occ 20.6%): correct math, starved engine.
//  (a) staging task map put consecutive lanes on different 24KB-apart channel
//      planes -> 2 lanes/64B line -> ~7.2 GB L2 traffic + ~6K TCP transactions
//      per dy per CU; (b) 152 KB LDS -> 1 block/CU, nothing to overlap with;
//  (c) prefetch ISSUE->FINISH distance was 2 KSTEPs (~50cy) vs ~200-600cy load.
//
// R8 fixes, same verified band-GEMM structure (7 tiles per dy, parity split):
//  - v-fastest task map (v=t%48, cg=t/48): 8 lanes/line, 4x less L2 traffic.
//  - A planes overlaid by B (A-frags live in VGPRs after prologue): LDS 56 KB
//    -> 2 blocks/CU; grid 1024 = exactly 2 clean rounds.
//  - single B buffer + register-held prefetch: all next-dy loads issued BEFORE
//    the 8 KSTEPs, cvt+ds_write after the post-compute barrier (T14 split);
//    prefetch distance = full compute phase.
//  - 512 thr (8 waves): 1536 staging tasks = exactly 3 rounds (24 prefetch
//    VGPR); wave 7 idles in MFMA (matrix pipe is not the bound).
//  - launch_bounds(512,4): VGPR cap 128 so 2 blocks (16 waves) fit per CU.
//    Falsifier: VGPR=128+scratch / WRITE_SIZE >> 85 MB => spilled, revert.

typedef short bf16x8 __attribute__((ext_vector_type(8)));
typedef float f32x4  __attribute__((ext_vector_type(4)));

constexpr int B_ = 8, C_ = 256, H_ = 64, W_ = 96, D_ = 21;
constexpr int THREADS = 512;                 // 8 waves
constexpr int CSTR = H_ * W_;                // 6144 floats per channel plane
constexpr size_t IMG = (size_t)C_ * CSTR;    // floats per batch image
constexpr int PLANE = 1536;                  // 16B granules per bf16 plane (48x32)
constexpr int LSZ = D_ * 49;                 // lout half size (padded rows)

__global__ __launch_bounds__(THREADS, 4) void corr_mfma(
    const float* __restrict__ in1,
    const float* __restrict__ in2,
    float* __restrict__ out)
{
    __shared__ uint4 ldsq[2 * PLANE];        // 48 KB: A hi/lo (prologue) then B hi/lo
    __shared__ float lout[2 * LSZ];          // 8.2 KB double-buffered gather grid

    const int id  = blockIdx.x;
    const int b   = id & 7;                  // b fastest -> XCD streams one batch
    const int p   = (id >> 3) & 1;           // x-parity sibling adjacent
    const int y   = id >> 4;                 // y-major
    const int tid = threadIdx.x;
    const int lane = tid & 63, li = lane & 15, gl = lane >> 4, wid = tid >> 6;

    // waves 0..6 -> the 7 useful band tiles (m-tile, v-tile); wave 7 idles in MFMA
    const int mw = (wid < 2) ? 0 : (wid < 5) ? 16 : 32;
    const int vw = (wid == 0 || wid == 2) ? 0 : (wid == 4 || wid == 6) ? 32 : 16;

    const int dylo = (y >= 21) ? 0 : ((21 - y) >> 1);
    const int dyhi = min(20, (83 - y) >> 1);

    // fp32 -> bf16 hi/lo split, store one 16B granule to each plane
    auto cvt = [&](const float (&f)[8], int gdst) {
        uint hv[4], lv[4];
        #pragma unroll
        for (int q = 0; q < 4; ++q) {
            uint a0 = __float_as_uint(f[2*q]), a1 = __float_as_uint(f[2*q+1]);
            hv[q] = (a1 & 0xFFFF0000u) | (a0 >> 16);
            float r0 = f[2*q]   - __uint_as_float(a0 & 0xFFFF0000u);
            float r1 = f[2*q+1] - __uint_as_float(a1 & 0xFFFF0000u);
            lv[q] = (__float_as_uint(r1) & 0xFFFF0000u) | (__float_as_uint(r0) >> 16);
        }
        ldsq[gdst]         = uint4{hv[0], hv[1], hv[2], hv[3]};
        ldsq[gdst + PLANE] = uint4{lv[0], lv[1], lv[2], lv[3]};
    };

    // v-fastest task map: consecutive lanes -> consecutive x -> 8 lanes/64B line
    auto stage_now = [&](const float* src) {
        #pragma unroll
        for (int n = 0; n < 3; ++n) {        // 1536 tasks = exactly 3 x 512
            int t = tid + n * THREADS;
            int v = t % 48, cg = t / 48;
            const float* g = src + (size_t)cg * 8 * CSTR + 2 * v;
            float f[8];
            #pragma unroll
            for (int j = 0; j < 8; ++j) f[j] = g[(size_t)j * CSTR];
            cvt(f, v * 32 + (cg ^ (v & 7)));
        }
    };

    // ---- prologue: stage A, load A-frags, overlay B(dylo) onto same region ----
    stage_now(in1 + (size_t)b * IMG + (size_t)y * W_ + p);
    for (int z = tid; z < 2 * LSZ; z += THREADS) lout[z] = 0.f;
    __syncthreads();

    bf16x8 ah[8], al[8];                     // resident across whole dy loop
    {
        const int rA = mw + li;
        #pragma unroll
        for (int k0 = 0; k0 < 8; ++k0) {
            int off = rA * 32 + ((4 * k0 + gl) ^ (rA & 7));
            ah[k0] = *(const bf16x8*)&ldsq[off];
            al[k0] = *(const bf16x8*)&ldsq[PLANE + off];
        }
    }
    __syncthreads();                         // A reads done -> region reusable

    stage_now(in2 + (size_t)b * IMG + (size_t)(y + 2 * dylo - 20) * W_ + p);

    int offB[8];
    {
        const int rB = vw + li;
        #pragma unroll
        for (int k0 = 0; k0 < 8; ++k0)
            offB[k0] = rB * 32 + ((4 * k0 + gl) ^ (rB & 7));
    }
    int pg[3], gof[3];
    {
        #pragma unroll
        for (int n = 0; n < 3; ++n) {
            int t = tid + n * THREADS;
            int v = t % 48, cg = t / 48;
            gof[n] = cg * 8 * CSTR + 2 * v;  // channel/x part (int: < 1.6M)
            pg[n]  = v * 32 + (cg ^ (v & 7));
        }
    }
    const float* gb2 = in2 + (size_t)b * IMG + p;
    __syncthreads();                         // B(dylo) ready

    // ---- dy loop: one banded 48x48x256 GEMM per dy ----
    float pf0[8], pf1[8], pf2[8];            // next-dy data held in registers
    for (int dy = dylo; dy <= dyhi; ++dy) {
        const bool pref = dy < dyhi;
        if (pref) {                          // issue ALL loads before compute
            const int ro = (y + 2 * (dy + 1) - 20) * W_;
            #pragma unroll
            for (int j = 0; j < 8; ++j) pf0[j] = gb2[gof[0] + ro + j * CSTR];
            #pragma unroll
            for (int j = 0; j < 8; ++j) pf1[j] = gb2[gof[1] + ro + j * CSTR];
            #pragma unroll
            for (int j = 0; j < 8; ++j) pf2[j] = gb2[gof[2] + ro + j * CSTR];
        }

        if (wid < 7) {
            f32x4 aH = {0.f,0.f,0.f,0.f}, aL = {0.f,0.f,0.f,0.f},
                  aM = {0.f,0.f,0.f,0.f};   // 3 independent MFMA chains
            #define KSTEP(k0) {                                                  \
                bf16x8 bh = *(const bf16x8*)&ldsq[offB[k0]];                     \
                bf16x8 bl = *(const bf16x8*)&ldsq[PLANE + offB[k0]];             \
                aL = __builtin_amdgcn_mfma_f32_16x16x32_bf16(al[k0], bh, aL, 0,0,0); \
                aM = __builtin_amdgcn_mfma_f32_16x16x32_bf16(ah[k0], bl, aM, 0,0,0); \
                aH = __builtin_amdgcn_mfma_f32_16x16x32_bf16(ah[k0], bh, aH, 0,0,0); }
            KSTEP(0) KSTEP(1) KSTEP(2) KSTEP(3)
            KSTEP(4) KSTEP(5) KSTEP(6) KSTEP(7)
            #undef KSTEP

            // scatter: C/D map col=lane&15 -> v, row=(lane>>4)*4+rr -> u (m89)
            const int lb = dy & 1;
            #pragma unroll
            for (int rr = 0; rr < 4; ++rr) {
                int u = mw + gl * 4 + rr, v = vw + li, dx = v - u + 10;
                if ((unsigned)dx < 21u)
                    lout[lb * LSZ + dx * 49 + u] =
                        (aH[rr] + (aL[rr] + aM[rr])) * (1.f / 256.f);
            }
        }
        __syncthreads();                     // B reads + scatter complete

        if (pref) {                          // cvt + ds_write next-dy B
            cvt(pf0, pg[0]); cvt(pf1, pg[1]); cvt(pf2, pg[2]);
        }
        if (wid < 7 && lane < 48) {          // write 21 dx rows, 3 per wave
            const int lb = dy & 1;
            #pragma unroll
            for (int q = 0; q < 3; ++q) {
                int dx = wid + 7 * q;
                float val = lout[lb * LSZ + dx * 49 + lane];
                out[(((size_t)(b * 441 + dy * D_ + dx)) * H_ + y) * W_
                    + p + 2 * lane] = val;
                lout[lb * LSZ + dx * 49 + lane] = 0.f;
            }
        }
        __syncthreads();                     // next B ready; lout half reusable
    }

    // ---- invalid-dy outputs are zero ----
    for (int dy = 0; dy < D_; ++dy) {
        if (dy >= dylo && dy <= dyhi) continue;
        for (int z = tid; z < D_ * 48; z += THREADS) {
            int dx = z / 48, u = z - dx * 48;
            out[(((size_t)(b * 441 + dy * D_ + dx)) * H_ + y) * W_
                + p + 2 * u] = 0.f;
        }
    }
}

extern "C" void kernel_launch(void* const* d_in, const int* in_sizes, int n_in,
                              void* d_out, int out_size, void* d_ws, size_t ws_size,
                              hipStream_t stream) {
    const float* in1 = (const float*)d_in[0];
    const float* in2 = (const float*)d_in[1];
    float* out = (float*)d_out;
    (void)in_sizes; (void)n_in; (void)d_ws; (void)ws_size; (void)out_size;
    dim3 grid(B_ * H_ * 2);                  // 1024: b fastest, then p, then y
    corr_mfma<<<grid, dim3(THREADS), 0, stream>>>(in1, in2, out);
}

// Round 6
// 324.502 us; speedup vs baseline: 1.8584x; 1.0373x over previous
//
#include <hip/hip_runtime.h>
#include <cstdint>
#include <cstddef>

// FlowNet-C correlation, MI355X — round 9: precomputed bf16 hi/lo + pure band-GEMM.
// B=8 C=256 H=64 W=96, PAD=MAXD=20, K=1, S1=1, S2=2 -> 441 output channels.
//
// R8 post-mortem (235us): VALUBusy 25% (~60us) = fp32->bf16 cvt done 21x
// redundantly (every y-block re-prepares row y2); plus 24 stride-24KB scalar
// gathers per thread per dy. MfmaUtil 8.6%.
//
// R9: kernel 1 converts in1+in2 to bf16 hi/lo ONCE into d_ws (96 MB), stored as
// per-(input,b,p,y) row-tiles of [cg][v] granules (granule = 8 channels @ one x,
// 16B) in exactly the linear order the GEMM kernel's LDS wants:
//   - convert reads coalesced (lane=x), the channel transpose is free: 8
//     row-loads leave channels cg*8..+7 of x=lane in ONE lane's registers.
//   - GEMM B staging = contiguous 48KB copy (6 uint4/thread), double-buffered,
//     issued a full compute phase ahead -> barrier drain free. No cvt, no
//     gathers, no swizzle ([cg][v] makes MFMA ds_reads 256B-contiguous per
//     16-lane group = bank-conflict-free).
// Fallback: ws_size < 96MB -> launch the proven R8 kernel (kept verbatim).

typedef short bf16x8 __attribute__((ext_vector_type(8)));
typedef float f32x4  __attribute__((ext_vector_type(4)));

constexpr int B_ = 8, C_ = 256, H_ = 64, W_ = 96, D_ = 21;
constexpr int CSTR = H_ * W_;                // 6144 floats per channel plane
constexpr size_t IMG = (size_t)C_ * CSTR;    // floats per batch image
constexpr int RT = 3072;                     // granules per row-tile (hi 1536 | lo 1536)
constexpr size_t WS_NEED = (size_t)2 * 8 * 2 * 64 * RT * 16;  // 100,663,296 B

// row-tile granule base for (inp, b, p, y)
__device__ __forceinline__ size_t rtbase(int inp, int b, int p, int y) {
    return ((size_t)(((inp * 8 + b) * 2 + p) * 64 + y)) * RT;
}

// fp32[8] -> packed bf16 hi (uint4) + lo (uint4)
__device__ __forceinline__ void packhl(const float (&f)[8], uint4& hi, uint4& lo) {
    uint hv[4], lv[4];
    #pragma unroll
    for (int q = 0; q < 4; ++q) {
        uint a0 = __float_as_uint(f[2*q]), a1 = __float_as_uint(f[2*q+1]);
        hv[q] = (a1 & 0xFFFF0000u) | (a0 >> 16);
        float r0 = f[2*q]   - __uint_as_float(a0 & 0xFFFF0000u);
        float r1 = f[2*q+1] - __uint_as_float(a1 & 0xFFFF0000u);
        lv[q] = (__float_as_uint(r1) & 0xFFFF0000u) | (__float_as_uint(r0) >> 16);
    }
    hi = uint4{hv[0], hv[1], hv[2], hv[3]};
    lo = uint4{lv[0], lv[1], lv[2], lv[3]};
}

// ---------------- kernel 1: fp32 -> bf16 hi/lo split, both inputs ----------------
__global__ __launch_bounds__(512, 2) void cvt_split(
    const float* __restrict__ in1, const float* __restrict__ in2,
    uint4* __restrict__ cv)
{
    const int id  = blockIdx.x;              // 1024 = inp(2) x b(8) x y(64)
    const int inp = id >> 9;
    const int rem = id & 511;
    const int b = rem >> 6, y = rem & 63;
    const int tid = threadIdx.x;
    const float* src = (inp ? in2 : in1) + (size_t)b * IMG + (size_t)y * W_;

    #pragma unroll
    for (int r = 0; r < 6; ++r) {            // 3072 tasks = 6 x 512
        int t  = tid + r * 512;
        int cg = t / 96, x = t - cg * 96;    // lane-consecutive x -> coalesced reads
        int p  = x & 1,  v = x >> 1;
        float f[8];
        #pragma unroll
        for (int j = 0; j < 8; ++j) f[j] = src[(size_t)(cg * 8 + j) * CSTR + x];
        uint4 hi, lo;
        packhl(f, hi, lo);
        size_t g = rtbase(inp, b, p, y) + cg * 48 + v;
        cv[g]        = hi;                   // same-parity lanes -> consecutive granules
        cv[g + 1536] = lo;
    }
}

// ---------------- kernel 2: banded 48x48x256 GEMM per (b,y,p,dy) ----------------
__global__ __launch_bounds__(512, 2) void corr_mfma2(
    const uint4* __restrict__ cv, float* __restrict__ out)
{
    __shared__ uint4 lds[2 * RT];            // 96 KB: two B buffers (A uses buf0 once)
    __shared__ float lout[D_ * 49];          // 4.1 KB gather grid

    const int id  = blockIdx.x;
    const int b   = id & 7;                  // b fastest -> XCD streams one batch
    const int p   = (id >> 3) & 1;
    const int y   = id >> 4;
    const int tid = threadIdx.x;
    const int lane = tid & 63, li = lane & 15, gl = lane >> 4, wid = tid >> 6;

    const int mw = (wid < 2) ? 0 : (wid < 5) ? 16 : 32;
    const int vw = (wid == 0 || wid == 2) ? 0 : (wid == 4 || wid == 6) ? 32 : 16;

    const int dylo = (y >= 21) ? 0 : ((21 - y) >> 1);
    const int dyhi = min(20, (83 - y) >> 1);

    // ---- prologue: copy A row-tile into buf0, read A-frags to registers ----
    {
        const uint4* s = cv + rtbase(0, b, p, y);
        #pragma unroll
        for (int n = 0; n < 6; ++n) {
            int g = (n * 8 + wid) * 64 + lane;   // 1KB contiguous per wave-instr
            lds[g] = s[g];
        }
    }
    for (int z = tid; z < D_ * 49; z += 512) lout[z] = 0.f;
    __syncthreads();

    bf16x8 ah[8], al[8];                     // resident across whole dy loop
    int offB[8];
    {
        const int rA = mw + li, rB = vw + li;
        #pragma unroll
        for (int k0 = 0; k0 < 8; ++k0) {
            int oa = (4 * k0 + gl) * 48 + rA;
            ah[k0] = *(const bf16x8*)&lds[oa];
            al[k0] = *(const bf16x8*)&lds[oa + 1536];
            offB[k0] = (4 * k0 + gl) * 48 + rB;
        }
    }
    __syncthreads();                         // A reads done -> buf0 reusable

    // ---- stage B(dylo) into buf0 ----
    {
        const uint4* s = cv + rtbase(1, b, p, y + 2 * dylo - 20);
        #pragma unroll
        for (int n = 0; n < 6; ++n) {
            int g = (n * 8 + wid) * 64 + lane;
            lds[g] = s[g];
        }
    }
    __syncthreads();

    // ---- dy loop ----
    int cur = 0;
    uint4 st[6];
    for (int dy = dylo; dy <= dyhi; ++dy) {
        const bool more = dy < dyhi;
        if (more) {                          // issue next-dy loads before compute
            const uint4* s = cv + rtbase(1, b, p, y + 2 * (dy + 1) - 20);
            #pragma unroll
            for (int n = 0; n < 6; ++n) st[n] = s[(n * 8 + wid) * 64 + lane];
        }

        if (wid < 7) {
            const int cb = cur * RT;
            f32x4 aH = {0.f,0.f,0.f,0.f}, aL = {0.f,0.f,0.f,0.f},
                  aM = {0.f,0.f,0.f,0.f};
            #define KSTEP(k0) {                                                  \
                bf16x8 bh = *(const bf16x8*)&lds[cb + offB[k0]];                 \
                bf16x8 bl = *(const bf16x8*)&lds[cb + 1536 + offB[k0]];          \
                aL = __builtin_amdgcn_mfma_f32_16x16x32_bf16(al[k0], bh, aL, 0,0,0); \
                aM = __builtin_amdgcn_mfma_f32_16x16x32_bf16(ah[k0], bl, aM, 0,0,0); \
                aH = __builtin_amdgcn_mfma_f32_16x16x32_bf16(ah[k0], bh, aH, 0,0,0); }
            KSTEP(0) KSTEP(1) KSTEP(2) KSTEP(3)
            KSTEP(4) KSTEP(5) KSTEP(6) KSTEP(7)
            #undef KSTEP
            #pragma unroll
            for (int rr = 0; rr < 4; ++rr) { // C/D: col=lane&15 -> v, row -> u
                int u = mw + gl * 4 + rr, v = vw + li, dx = v - u + 10;
                if ((unsigned)dx < 21u)
                    lout[dx * 49 + u] = (aH[rr] + (aL[rr] + aM[rr])) * (1.f / 256.f);
            }
        }
        __syncthreads();                     // staged loads landed? no: regs. scatter visible; B reads done

        if (more) {                          // ds_write next-dy B (waits its loads)
            const int nb = (cur ^ 1) * RT;
            #pragma unroll
            for (int n = 0; n < 6; ++n) lds[nb + (n * 8 + wid) * 64 + lane] = st[n];
        }
        float ov[3];
        const bool do_out = (wid < 7) && (lane < 48);
        if (do_out) {                        // read + re-zero lout
            #pragma unroll
            for (int q = 0; q < 3; ++q) {
                int dx = wid + 7 * q;
                ov[q] = lout[dx * 49 + lane];
                lout[dx * 49 + lane] = 0.f;
            }
        }
        __syncthreads();                     // next B + lout ops complete
        if (do_out) {                        // fire-and-forget; drains under next compute
            #pragma unroll
            for (int q = 0; q < 3; ++q) {
                int dx = wid + 7 * q;
                out[(((size_t)(b * 441 + dy * D_ + dx)) * H_ + y) * W_
                    + p + 2 * lane] = ov[q];
            }
        }
        cur ^= 1;
    }

    // ---- invalid-dy outputs are zero ----
    for (int dy = 0; dy < D_; ++dy) {
        if (dy >= dylo && dy <= dyhi) continue;
        for (int z = tid; z < D_ * 48; z += 512) {
            int dx = z / 48, u = z - dx * 48;
            out[(((size_t)(b * 441 + dy * D_ + dx)) * H_ + y) * W_
                + p + 2 * u] = 0.f;
        }
    }
}

// ---------------- fallback: R8 kernel verbatim (used if ws too small) ----------------
constexpr int PLANE = 1536;
constexpr int LSZ = D_ * 49;

__global__ __launch_bounds__(512, 4) void corr_fb(
    const float* __restrict__ in1, const float* __restrict__ in2,
    float* __restrict__ out)
{
    __shared__ uint4 ldsq[2 * PLANE];
    __shared__ float lout[2 * LSZ];
    const int id  = blockIdx.x;
    const int b   = id & 7;
    const int p   = (id >> 3) & 1;
    const int y   = id >> 4;
    const int tid = threadIdx.x;
    const int lane = tid & 63, li = lane & 15, gl = lane >> 4, wid = tid >> 6;
    const int mw = (wid < 2) ? 0 : (wid < 5) ? 16 : 32;
    const int vw = (wid == 0 || wid == 2) ? 0 : (wid == 4 || wid == 6) ? 32 : 16;
    const int dylo = (y >= 21) ? 0 : ((21 - y) >> 1);
    const int dyhi = min(20, (83 - y) >> 1);

    auto cvt = [&](const float (&f)[8], int gdst) {
        uint4 hi, lo;
        packhl(f, hi, lo);
        ldsq[gdst]         = hi;
        ldsq[gdst + PLANE] = lo;
    };
    auto stage_now = [&](const float* src) {
        #pragma unroll
        for (int n = 0; n < 3; ++n) {
            int t = tid + n * 512;
            int v = t % 48, cg = t / 48;
            const float* g = src + (size_t)cg * 8 * CSTR + 2 * v;
            float f[8];
            #pragma unroll
            for (int j = 0; j < 8; ++j) f[j] = g[(size_t)j * CSTR];
            cvt(f, v * 32 + (cg ^ (v & 7)));
        }
    };

    stage_now(in1 + (size_t)b * IMG + (size_t)y * W_ + p);
    for (int z = tid; z < 2 * LSZ; z += 512) lout[z] = 0.f;
    __syncthreads();
    bf16x8 ah[8], al[8];
    {
        const int rA = mw + li;
        #pragma unroll
        for (int k0 = 0; k0 < 8; ++k0) {
            int off = rA * 32 + ((4 * k0 + gl) ^ (rA & 7));
            ah[k0] = *(const bf16x8*)&ldsq[off];
            al[k0] = *(const bf16x8*)&ldsq[PLANE + off];
        }
    }
    __syncthreads();
    stage_now(in2 + (size_t)b * IMG + (size_t)(y + 2 * dylo - 20) * W_ + p);
    int offB[8];
    {
        const int rB = vw + li;
        #pragma unroll
        for (int k0 = 0; k0 < 8; ++k0)
            offB[k0] = rB * 32 + ((4 * k0 + gl) ^ (rB & 7));
    }
    int pg[3], gof[3];
    {
        #pragma unroll
        for (int n = 0; n < 3; ++n) {
            int t = tid + n * 512;
            int v = t % 48, cg = t / 48;
            gof[n] = cg * 8 * CSTR + 2 * v;
            pg[n]  = v * 32 + (cg ^ (v & 7));
        }
    }
    const float* gb2 = in2 + (size_t)b * IMG + p;
    __syncthreads();

    float pf0[8], pf1[8], pf2[8];
    for (int dy = dylo; dy <= dyhi; ++dy) {
        const bool pref = dy < dyhi;
        if (pref) {
            const int ro = (y + 2 * (dy + 1) - 20) * W_;
            #pragma unroll
            for (int j = 0; j < 8; ++j) pf0[j] = gb2[gof[0] + ro + j * CSTR];
            #pragma unroll
            for (int j = 0; j < 8; ++j) pf1[j] = gb2[gof[1] + ro + j * CSTR];
            #pragma unroll
            for (int j = 0; j < 8; ++j) pf2[j] = gb2[gof[2] + ro + j * CSTR];
        }
        if (wid < 7) {
            f32x4 aH = {0.f,0.f,0.f,0.f}, aL = {0.f,0.f,0.f,0.f},
                  aM = {0.f,0.f,0.f,0.f};
            #define KSTEP(k0) {                                                  \
                bf16x8 bh = *(const bf16x8*)&ldsq[offB[k0]];                     \
                bf16x8 bl = *(const bf16x8*)&ldsq[PLANE + offB[k0]];             \
                aL = __builtin_amdgcn_mfma_f32_16x16x32_bf16(al[k0], bh, aL, 0,0,0); \
                aM = __builtin_amdgcn_mfma_f32_16x16x32_bf16(ah[k0], bl, aM, 0,0,0); \
                aH = __builtin_amdgcn_mfma_f32_16x16x32_bf16(ah[k0], bh, aH, 0,0,0); }
            KSTEP(0) KSTEP(1) KSTEP(2) KSTEP(3)
            KSTEP(4) KSTEP(5) KSTEP(6) KSTEP(7)
            #undef KSTEP
            const int lb = dy & 1;
            #pragma unroll
            for (int rr = 0; rr < 4; ++rr) {
                int u = mw + gl * 4 + rr, v = vw + li, dx = v - u + 10;
                if ((unsigned)dx < 21u)
                    lout[lb * LSZ + dx * 49 + u] =
                        (aH[rr] + (aL[rr] + aM[rr])) * (1.f / 256.f);
            }
        }
        __syncthreads();
        if (pref) { cvt(pf0, pg[0]); cvt(pf1, pg[1]); cvt(pf2, pg[2]); }
        if (wid < 7 && lane < 48) {
            const int lb = dy & 1;
            #pragma unroll
            for (int q = 0; q < 3; ++q) {
                int dx = wid + 7 * q;
                float val = lout[lb * LSZ + dx * 49 + lane];
                out[(((size_t)(b * 441 + dy * D_ + dx)) * H_ + y) * W_
                    + p + 2 * lane] = val;
                lout[lb * LSZ + dx * 49 + lane] = 0.f;
            }
        }
        __syncthreads();
    }
    for (int dy = 0; dy < D_; ++dy) {
        if (dy >= dylo && dy <= dyhi) continue;
        for (int z = tid; z < D_ * 48; z += 512) {
            int dx = z / 48, u = z - dx * 48;
            out[(((size_t)(b * 441 + dy * D_ + dx)) * H_ + y) * W_
                + p + 2 * u] = 0.f;
        }
    }
}

extern "C" void kernel_launch(void* const* d_in, const int* in_sizes, int n_in,
                              void* d_out, int out_size, void* d_ws, size_t ws_size,
                              hipStream_t stream) {
    const float* in1 = (const float*)d_in[0];
    const float* in2 = (const float*)d_in[1];
    float* out = (float*)d_out;
    (void)in_sizes; (void)n_in; (void)out_size;
    if (d_ws != nullptr && ws_size >= WS_NEED) {
        uint4* cv = (uint4*)d_ws;
        cvt_split<<<dim3(1024), dim3(512), 0, stream>>>(in1, in2, cv);
        corr_mfma2<<<dim3(1024), dim3(512), 0, stream>>>(cv, out);
    } else {
        corr_fb<<<dim3(1024), dim3(512), 0, stream>>>(in1, in2, out);
    }
}